// Round 1
// 330.014 us; speedup vs baseline: 1.0011x; 1.0011x over previous
//
#include <hip/hip_runtime.h>
#include <hip/hip_bf16.h>

// Attn: energies = out_state @ (history @ W.T).T ; softmax rows.
// (bias dropped: os.b is constant per softmax row -> cancels in softmax.)
// S2=S1=4096, N=1024. fp32 in/out. bf16 hi/lo 3-term GEMM folded into K=3072.
// R7 (kept): 256x128 stage-2 tile, dbuf global_load_lds, 161 us @ MfmaUtil 27%.
// R9 (reverted): hybrid reg-staging -> VGPR 168, 1 block/CU, 378 us.
// R10: slot audit -- ~2000-cyc barrier slot regardless of staged bytes ->
//      latency-bound on the __syncthreads() vmcnt(0) drain.
// R11: counted-vmcnt depth-2 pipeline (T3/T4). 3 LDS buffers (72 KB, still
//      2 blocks/CU), raw s_barrier + inline-asm s_waitcnt vmcnt(6): each
//      slab's DMAs issued 2 iters ahead, later prefetches stay in flight
//      ACROSS the barrier. lgkmcnt(0) folded into the wait so no wave
//      crosses the barrier with LDS reads pending (WAR on recycled buf).

typedef __bf16 bf16x8 __attribute__((ext_vector_type(8)));
typedef float f32x4 __attribute__((ext_vector_type(4)));
typedef unsigned short u16x4 __attribute__((ext_vector_type(4)));

__device__ __forceinline__ unsigned short f2bf(float x) {
  unsigned int u = __float_as_uint(x);
  u += 0x7fffu + ((u >> 16) & 1u);   // RNE
  return (unsigned short)(u >> 16);
}
__device__ __forceinline__ float bf2f(unsigned short h) {
  return __uint_as_float(((unsigned int)h) << 16);
}

__device__ __forceinline__ void async_copy_16(void* lds, const void* gsrc) {
  __builtin_amdgcn_global_load_lds(
      (const __attribute__((address_space(1))) void*)gsrc,
      (__attribute__((address_space(3))) void*)lds, 16, 0, 0);
}

// Split fp32 X[rows x 1024] -> Y[rows x 3072] bf16.
// bside=0 (A-operand): [hi | lo | hi]   bside=1 (B-operand): [hi | hi | lo]
__global__ __launch_bounds__(256)
void split_kernel(const float* __restrict__ X, unsigned short* __restrict__ Y, int bside) {
  const size_t row = blockIdx.x;
  const int c4 = threadIdx.x;                       // 256 threads x 4 cols = 1024
  float4 x = ((const float4*)(X + row * 1024))[c4];
  float xs[4] = {x.x, x.y, x.z, x.w};
  u16x4 h, l;
#pragma unroll
  for (int i = 0; i < 4; ++i) {
    unsigned short hh = f2bf(xs[i]);
    h[i] = hh;
    l[i] = f2bf(xs[i] - bf2f(hh));
  }
  u16x4* y0 = (u16x4*)(Y + row * 3072 + (size_t)c4 * 4);  // 256 u16x4 per 1024 cols
  if (bside) { y0[0] = h; y0[256] = h; y0[512] = l; }
  else       { y0[0] = h; y0[256] = l; y0[512] = h; }
}

// C[M,N] = A[M,K] . B[N,K]^T, bf16 in, fp32 acc. 256 threads, wave grid 2x2,
// wave tile (BM/2) x (BN/2). Fragment-ordered LDS per 32-k sub-slab: 16-row
// group g, k-seg s (8 bf16), row r at byte g*1024 + s*256 + r*16 == group
// base + lane*16 (lane = s*16+r) -> matches global_load_lds wave-uniform-
// base+lane*16; 2-way bank aliasing only (free) on ds_read_b128 frag loads.
// R11 pipeline: 3 buffers, depth-2 prefetch. Steady-state iter:
//   s_waitcnt vmcnt(DM) lgkmcnt(0)   // drain ONLY slab t's DMAs (oldest 6);
//                                    // slab t+1's 6 stay in flight
//   s_barrier                        // all waves' slab-t data now in LDS
//   stage slab t+2 into buf (cur+2)%3  // buffer read at iter t-1: safe (WAR
//                                      // closed by lgkmcnt(0)+barrier)
//   compute(cur)
// Last slab peeled with vmcnt(0).
// EPI=0: store fp32 C. EPI=1: write [hi|hi|lo] split of acc into P2.
template <int BM, int BN, int KU, int EPI, int GM, int GN, int RM, int RN>
__global__ __launch_bounds__(256)
void gemm_bt(const unsigned short* __restrict__ A,
             const unsigned short* __restrict__ B,
             float* __restrict__ C,
             unsigned short* __restrict__ P2,
             int M, int N, int K) {
  constexpr int MT = BM / 32;            // m-frags per wave
  constexpr int NT = BN / 32;            // n-frags per wave
  constexpr int NA = BM / 64;            // A DMA chunks per wave per sub-slab
  constexpr int NB = BN / 64;            // B DMA chunks per wave per sub-slab
  constexpr int BK = 32 * KU;            // k per staged slab
  constexpr int DM = KU * (NA + NB);     // DMA instrs per slab per wave
  __shared__ unsigned short As[3][KU * BM * 32];
  __shared__ unsigned short Bs[3][KU * BN * 32];

  const int tid = threadIdx.x;
  const int w = tid >> 6;
  const int lane = tid & 63;
  const int wm = w >> 1, wn = w & 1;
  const int lr = lane & 15;              // m/n index within 16-tile
  const int ls = lane >> 4;              // k-segment (8 bf16 each)

  // XCD-aware super-tile swizzle
  const int id = blockIdx.x;
  const int xcd = id & 7;
  const int j = id >> 3;
  const int bm = ((xcd % (GM / RM)) * RM + (j % RM)) * BM;
  const int bn = ((xcd / (GM / RM)) * RN + (j / RM)) * BN;

  // staging source pointers (hoisted; advance by k-offset each issue)
  const unsigned short* pa[NA];
#pragma unroll
  for (int c = 0; c < NA; ++c)
    pa[c] = A + (size_t)(bm + (w * NA + c) * 16 + lr) * K + ls * 8;
  const unsigned short* pb[NB];
#pragma unroll
  for (int c = 0; c < NB; ++c)
    pb[c] = B + (size_t)(bn + (w * NB + c) * 16 + lr) * K + ls * 8;

  f32x4 acc[MT][NT] = {};

  // stage one BK-slab (KU sub-slabs) starting at k-offset kt into buffer buf
  auto stage = [&](int buf, int kt) {
#pragma unroll
    for (int u = 0; u < KU; ++u) {
#pragma unroll
      for (int c = 0; c < NA; ++c)
        async_copy_16(&As[buf][u * BM * 32 + (w * NA + c) * 512], pa[c] + kt + u * 32);
#pragma unroll
      for (int c = 0; c < NB; ++c)
        async_copy_16(&Bs[buf][u * BN * 32 + (w * NB + c) * 512], pb[c] + kt + u * 32);
    }
  };

  auto compute = [&](int buf) {
#pragma unroll
    for (int u = 0; u < KU; ++u) {
      bf16x8 af[MT], bfr[NT];
#pragma unroll
      for (int mt = 0; mt < MT; ++mt)
        af[mt] = *(const bf16x8*)&As[buf][u * BM * 32 + (wm * MT + mt) * 512 + ls * 128 + lr * 8];
#pragma unroll
      for (int nt = 0; nt < NT; ++nt)
        bfr[nt] = *(const bf16x8*)&Bs[buf][u * BN * 32 + (wn * NT + nt) * 512 + ls * 128 + lr * 8];
#pragma unroll
      for (int mt = 0; mt < MT; ++mt)
#pragma unroll
        for (int nt = 0; nt < NT; ++nt)
          acc[mt][nt] = __builtin_amdgcn_mfma_f32_16x16x32_bf16(af[mt], bfr[nt], acc[mt][nt], 0, 0, 0);
    }
  };

  // prologue: stage slabs 0 and 1 (depth-2)
  stage(0, 0);
  stage(1, BK);

  int cur = 0;
  const int Klast = K - BK;
  for (int kt = 0; kt < Klast; kt += BK) {
    // drain oldest DM loads (= slab cur); keep next slab's DM in flight.
    asm volatile("s_waitcnt vmcnt(%0) lgkmcnt(0)" :: "n"(DM) : "memory");
    __builtin_amdgcn_s_barrier();
    __builtin_amdgcn_sched_barrier(0);
    if (kt + 2 * BK < K) {
      int nb = cur - 1; if (nb < 0) nb = 2;     // (cur+2)%3
      stage(nb, kt + 2 * BK);
    }
    compute(cur);
    cur = (cur == 2) ? 0 : cur + 1;
  }
  // peeled last slab: nothing left in flight beyond it -> full drain
  asm volatile("s_waitcnt vmcnt(0) lgkmcnt(0)" ::: "memory");
  __builtin_amdgcn_s_barrier();
  __builtin_amdgcn_sched_barrier(0);
  compute(cur);

  // Epilogue. C/D layout (m89/m91): col(n) = lane&15, row(m) = (lane>>4)*4 + reg.
  const int cm0 = bm + wm * (BM / 2);
  const int cn0 = bn + wn * (BN / 2);
#pragma unroll
  for (int mt = 0; mt < MT; ++mt) {
#pragma unroll
    for (int nt = 0; nt < NT; ++nt) {
      const int col = cn0 + nt * 16 + lr;
      const int row0 = cm0 + mt * 16 + ls * 4;
      if constexpr (EPI == 0) {
#pragma unroll
        for (int r = 0; r < 4; ++r)
          C[(size_t)(row0 + r) * N + col] = acc[mt][nt][r];
      } else {
#pragma unroll
        for (int r = 0; r < 4; ++r) {
          const float p = acc[mt][nt][r];
          const unsigned short h = f2bf(p);
          const unsigned short l = f2bf(p - bf2f(h));
          const size_t base = (size_t)(row0 + r) * 3072 + col;
          P2[base] = h;
          P2[base + 1024] = h;
          P2[base + 2048] = l;
        }
      }
    }
  }
}

// In-place row softmax, N=4096, one block per row, 16 floats/thread in regs.
__global__ __launch_bounds__(256)
void softmax_inplace(float* __restrict__ C, int N) {
  float4* r4 = (float4*)(C + (size_t)blockIdx.x * N);
  const int t = threadIdx.x;
  float4 v[4];
  float mx = -3.0e38f;
#pragma unroll
  for (int i = 0; i < 4; ++i) {
    v[i] = r4[t + i * 256];
    mx = fmaxf(mx, fmaxf(fmaxf(v[i].x, v[i].y), fmaxf(v[i].z, v[i].w)));
  }
#pragma unroll
  for (int o = 32; o; o >>= 1) mx = fmaxf(mx, __shfl_xor(mx, o, 64));
  __shared__ float smax[4], ssum[4];
  const int w = t >> 6;
  if ((t & 63) == 0) smax[w] = mx;
  __syncthreads();
  mx = fmaxf(fmaxf(smax[0], smax[1]), fmaxf(smax[2], smax[3]));
  float s = 0.f;
#pragma unroll
  for (int i = 0; i < 4; ++i) {
    v[i].x = __expf(v[i].x - mx);
    v[i].y = __expf(v[i].y - mx);
    v[i].z = __expf(v[i].z - mx);
    v[i].w = __expf(v[i].w - mx);
    s += (v[i].x + v[i].y) + (v[i].z + v[i].w);
  }
#pragma unroll
  for (int o = 32; o; o >>= 1) s += __shfl_xor(s, o, 64);
  if ((t & 63) == 0) ssum[w] = s;
  __syncthreads();
  const float inv = 1.0f / (ssum[0] + ssum[1] + ssum[2] + ssum[3]);
#pragma unroll
  for (int i = 0; i < 4; ++i) {
    v[i].x *= inv; v[i].y *= inv; v[i].z *= inv; v[i].w *= inv;
    r4[t + i * 256] = v[i];
  }
}

extern "C" void kernel_launch(void* const* d_in, const int* in_sizes, int n_in,
                              void* d_out, int out_size, void* d_ws, size_t ws_size,
                              hipStream_t stream) {
  const float* out_state = (const float*)d_in[0];  // [4096,1024]
  const float* history   = (const float*)d_in[1];  // [4096,1024]
  const float* W         = (const float*)d_in[2];  // [1024,1024]
  float* out = (float*)d_out;                      // [4096,4096]

  unsigned short* H2 = (unsigned short*)d_ws;                 // 4096x3072
  unsigned short* W2 = H2 + (size_t)4096 * 3072;              // 1024x3072
  unsigned short* A2 = W2 + (size_t)1024 * 3072;              // 4096x3072
  unsigned short* P2 = A2 + (size_t)4096 * 3072;              // 4096x3072

  split_kernel<<<4096, 256, 0, stream>>>(history, H2, 0);
  split_kernel<<<1024, 256, 0, stream>>>(W, W2, 1);
  split_kernel<<<4096, 256, 0, stream>>>(out_state, A2, 0);

  // proj -> P2 split. BM=128, BN=64, KU=2 (BK=64): 48 slabs, depth-2
  // counted-vmcnt pipeline, LDS 72 KB -> 2 blocks/CU. 512 blocks.
  gemm_bt<128, 64, 2, 1, 32, 16, 8, 8><<<512, 256, 0, stream>>>(
      H2, W2, nullptr, P2, 4096, 1024, 3072);

  // energies -> d_out. BM=256, BN=128, KU=1: 96 slabs, depth-2 pipeline,
  // LDS 72 KB -> 2 blocks/CU. 512 blocks.
  gemm_bt<256, 128, 1, 0, 16, 32, 8, 8><<<512, 256, 0, stream>>>(
      A2, P2, out, nullptr, 4096, 4096, 3072);

  softmax_inplace<<<4096, 256, 0, stream>>>(out, 4096);
}

// Round 2
// 300.772 us; speedup vs baseline: 1.0984x; 1.0972x over previous
//
#include <hip/hip_runtime.h>
#include <hip/hip_bf16.h>

// Attn: energies = out_state @ (history @ W.T).T ; softmax rows.
// (bias dropped: constant per softmax row -> cancels.)
// S2=S1=4096, N=1024. fp32 in/out. bf16 hi/lo 3-term GEMM folded into K=3072.
// R10/R11 lesson: counted vmcnt WITHOUT phase-split is null (matches catalog
// regime gate: T4 requires T3). Stage-2 = 656 TF == m233's 2-phase 607 TF.
// R12: full T3+T4+T5 port (m201 rhythm). Per 32k-tile: 2 phases of
// {ds_read 8/4 x b128 + issue DMAs for tile t+3 -> barrier -> lgkmcnt(0) ->
//  setprio(1) 16 MFMA setprio(0) -> barrier}, 4 LDS buffers, depth-3
// prefetch, boundary s_waitcnt vmcnt(2*DM) (never 0 in main loop).
// Stage-2: 256x256 tile, 8 waves, 256 blocks. Stage-1: 128x128, 8 waves,
// 256 blocks (was the hidden ~125 us elephant at ~200 TF).

typedef __bf16 bf16x8 __attribute__((ext_vector_type(8)));
typedef float f32x4 __attribute__((ext_vector_type(4)));
typedef unsigned short u16x4 __attribute__((ext_vector_type(4)));

__device__ __forceinline__ unsigned short f2bf(float x) {
  unsigned int u = __float_as_uint(x);
  u += 0x7fffu + ((u >> 16) & 1u);   // RNE
  return (unsigned short)(u >> 16);
}
__device__ __forceinline__ float bf2f(unsigned short h) {
  return __uint_as_float(((unsigned int)h) << 16);
}

__device__ __forceinline__ void async_copy_16(void* lds, const void* gsrc) {
  __builtin_amdgcn_global_load_lds(
      (const __attribute__((address_space(1))) void*)gsrc,
      (__attribute__((address_space(3))) void*)lds, 16, 0, 0);
}

// compiler-fence + hw barrier: the "" memory clobber pins IR/MI-level memory
// op ordering across the raw s_barrier (which has no modeled mem effects).
__device__ __forceinline__ void barrier_fenced() {
  asm volatile("" ::: "memory");
  __builtin_amdgcn_s_barrier();
  asm volatile("" ::: "memory");
}

// Split fp32 X[rows x 1024] -> Y[rows x 3072] bf16.
// bside=0 (A-operand): [hi | lo | hi]   bside=1 (B-operand): [hi | hi | lo]
__global__ __launch_bounds__(256)
void split_kernel(const float* __restrict__ X, unsigned short* __restrict__ Y, int bside) {
  const size_t row = blockIdx.x;
  const int c4 = threadIdx.x;                       // 256 threads x 4 cols = 1024
  float4 x = ((const float4*)(X + row * 1024))[c4];
  float xs[4] = {x.x, x.y, x.z, x.w};
  u16x4 h, l;
#pragma unroll
  for (int i = 0; i < 4; ++i) {
    unsigned short hh = f2bf(xs[i]);
    h[i] = hh;
    l[i] = f2bf(xs[i] - bf2f(hh));
  }
  u16x4* y0 = (u16x4*)(Y + row * 3072 + (size_t)c4 * 4);
  if (bside) { y0[0] = h; y0[256] = h; y0[512] = l; }
  else       { y0[0] = h; y0[256] = l; y0[512] = h; }
}

// C[M,N] = A[M,K] . B[N,K]^T, bf16 in, fp32 acc. WM*WN waves (wave tile
// (BM/WM) x (BN/WN)). Fragment-ordered LDS per 32-k tile: 16-row group g at
// byte g*1024 + lane*16 (lane = kseg*16 + row) -> matches global_load_lds
// wave-uniform-base + lane*16; 2-way bank aliasing only (free) on
// ds_read_b128 frag loads. 4 buffers, depth-3 prefetch, counted vmcnt.
// Per tile: PH phases; phase 0 reads A-frags[0,M0) + ALL B-frags, phase 1
// (PH==2) reads A-frags[M0,MT). Each phase: reads + DMA-issue, barrier,
// lgkmcnt(0), setprio(1), M0*NT MFMA, setprio(0), barrier. Boundary:
// vmcnt(2*DM) steady / DM / 0 at tail, barrier publishes tile t+1.
// EPI=0: store fp32 C. EPI=1: write [hi|hi|lo] split of acc into P2.
template <int BM, int BN, int WM, int WN, int PH, int EPI,
          int GM, int RM, int RN, int KC>
__global__ __launch_bounds__(WM * WN * 64, 2)
void gemm_bt(const unsigned short* __restrict__ A,
             const unsigned short* __restrict__ B,
             float* __restrict__ C,
             unsigned short* __restrict__ P2,
             int M, int N) {
  constexpr int NWAVE = WM * WN;
  constexpr int MT = BM / (WM * 16);     // m-frags per wave
  constexpr int NT = BN / (WN * 16);     // n-frags per wave
  constexpr int M0 = (PH == 2) ? MT / 2 : MT;
  constexpr int NA = (BM / 16) / NWAVE;  // A DMA chunks per wave per tile
  constexpr int NB = (BN / 16) / NWAVE;  // B DMA chunks per wave per tile
  constexpr int DM = NA + NB;
  constexpr int NTILES = KC / 32;
  __shared__ unsigned short As[4][BM * 32];
  __shared__ unsigned short Bs[4][BN * 32];

  const int tid = threadIdx.x;
  const int w = tid >> 6;
  const int lane = tid & 63;
  const int wm = w / WN, wn = w % WN;
  const int lr = lane & 15;              // row index within 16-group
  const int ls = lane >> 4;              // k-segment (8 bf16 each)

  // XCD-aware super-tile swizzle (grid = 256 = 8 XCDs x 32, bijective)
  const int id = blockIdx.x;
  const int xcd = id & 7;
  const int j = id >> 3;
  const int bm = ((xcd % (GM / RM)) * RM + (j % RM)) * BM;
  const int bn = ((xcd / (GM / RM)) * RN + (j / RM)) * BN;

  const unsigned short* pa[NA];
#pragma unroll
  for (int c = 0; c < NA; ++c)
    pa[c] = A + (size_t)(bm + (w * NA + c) * 16 + lr) * KC + ls * 8;
  const unsigned short* pb[NB];
#pragma unroll
  for (int c = 0; c < NB; ++c)
    pb[c] = B + (size_t)(bn + (w * NB + c) * 16 + lr) * KC + ls * 8;

  f32x4 acc[MT][NT] = {};

  auto stageA = [&](int buf, int t) {
#pragma unroll
    for (int c = 0; c < NA; ++c)
      async_copy_16(&As[buf][(w * NA + c) * 512], pa[c] + t * 32);
  };
  auto stageB = [&](int buf, int t) {
#pragma unroll
    for (int c = 0; c < NB; ++c)
      async_copy_16(&Bs[buf][(w * NB + c) * 512], pb[c] + t * 32);
  };

  // prologue: stage tiles 0..2 (depth-3), wait tile 0, publish
  stageA(0, 0); stageB(0, 0);
  stageA(1, 1); stageB(1, 1);
  stageA(2, 2); stageB(2, 2);
  asm volatile("s_waitcnt vmcnt(%0)" :: "n"(2 * DM) : "memory");
  barrier_fenced();

#pragma unroll 1
  for (int t = 0; t < NTILES; ++t) {
    const int buf = t & 3;
    const int nbuf = (t + 3) & 3;
    const bool st = (t < NTILES - 3);

    // ---- phase 0: A-frags [0,M0) + all B-frags; issue A DMAs for t+3 ----
    bf16x8 af[M0], bfr[NT];
#pragma unroll
    for (int mt = 0; mt < M0; ++mt)
      af[mt] = *(const bf16x8*)&As[buf][(wm * MT + mt) * 512 + ls * 128 + lr * 8];
#pragma unroll
    for (int nt = 0; nt < NT; ++nt)
      bfr[nt] = *(const bf16x8*)&Bs[buf][(wn * NT + nt) * 512 + ls * 128 + lr * 8];
    if (st) stageA(nbuf, t + 3);
    if constexpr (PH == 1) { if (st) stageB(nbuf, t + 3); }
    barrier_fenced();
    asm volatile("s_waitcnt lgkmcnt(0)" ::: "memory");
    __builtin_amdgcn_sched_barrier(0);
    __builtin_amdgcn_s_setprio(1);
#pragma unroll
    for (int mt = 0; mt < M0; ++mt)
#pragma unroll
      for (int nt = 0; nt < NT; ++nt)
        acc[mt][nt] = __builtin_amdgcn_mfma_f32_16x16x32_bf16(af[mt], bfr[nt], acc[mt][nt], 0, 0, 0);
    __builtin_amdgcn_s_setprio(0);
    __builtin_amdgcn_sched_barrier(0);

    // ---- phase 1 (PH==2): A-frags [M0,MT), reuse B; issue B DMAs ----
    if constexpr (PH == 2) {
      barrier_fenced();
      bf16x8 ag[MT - M0];
#pragma unroll
      for (int mt = 0; mt < MT - M0; ++mt)
        ag[mt] = *(const bf16x8*)&As[buf][(wm * MT + M0 + mt) * 512 + ls * 128 + lr * 8];
      if (st) stageB(nbuf, t + 3);
      barrier_fenced();
      asm volatile("s_waitcnt lgkmcnt(0)" ::: "memory");
      __builtin_amdgcn_sched_barrier(0);
      __builtin_amdgcn_s_setprio(1);
#pragma unroll
      for (int mt = 0; mt < MT - M0; ++mt)
#pragma unroll
        for (int nt = 0; nt < NT; ++nt)
          acc[M0 + mt][nt] = __builtin_amdgcn_mfma_f32_16x16x32_bf16(ag[mt], bfr[nt], acc[M0 + mt][nt], 0, 0, 0);
      __builtin_amdgcn_s_setprio(0);
      __builtin_amdgcn_sched_barrier(0);
    }

    // ---- boundary: tile t+1 must be landed; keep t+2/t+3 in flight ----
    if (t < NTILES - 3)
      asm volatile("s_waitcnt vmcnt(%0)" :: "n"(2 * DM) : "memory");
    else if (t == NTILES - 3)
      asm volatile("s_waitcnt vmcnt(%0)" :: "n"(DM) : "memory");
    else
      asm volatile("s_waitcnt vmcnt(0)" ::: "memory");
    barrier_fenced();
  }

  // Epilogue. C/D layout (m89/m91): col(n) = lane&15, row(m) = (lane>>4)*4 + reg.
  const int cm0 = bm + wm * (BM / WM);
  const int cn0 = bn + wn * (BN / WN);
#pragma unroll
  for (int mt = 0; mt < MT; ++mt) {
#pragma unroll
    for (int nt = 0; nt < NT; ++nt) {
      const int col = cn0 + nt * 16 + lr;
      const int row0 = cm0 + mt * 16 + ls * 4;
      if constexpr (EPI == 0) {
#pragma unroll
        for (int r = 0; r < 4; ++r)
          C[(size_t)(row0 + r) * N + col] = acc[mt][nt][r];
      } else {
#pragma unroll
        for (int r = 0; r < 4; ++r) {
          const float p = acc[mt][nt][r];
          const unsigned short h = f2bf(p);
          const unsigned short l = f2bf(p - bf2f(h));
          const size_t base = (size_t)(row0 + r) * 3072 + col;
          P2[base] = h;
          P2[base + 1024] = h;
          P2[base + 2048] = l;
        }
      }
    }
  }
}

// In-place row softmax, N=4096, one block per row, 16 floats/thread in regs.
__global__ __launch_bounds__(256)
void softmax_inplace(float* __restrict__ C, int N) {
  float4* r4 = (float4*)(C + (size_t)blockIdx.x * N);
  const int t = threadIdx.x;
  float4 v[4];
  float mx = -3.0e38f;
#pragma unroll
  for (int i = 0; i < 4; ++i) {
    v[i] = r4[t + i * 256];
    mx = fmaxf(mx, fmaxf(fmaxf(v[i].x, v[i].y), fmaxf(v[i].z, v[i].w)));
  }
#pragma unroll
  for (int o = 32; o; o >>= 1) mx = fmaxf(mx, __shfl_xor(mx, o, 64));
  __shared__ float smax[4], ssum[4];
  const int w = t >> 6;
  if ((t & 63) == 0) smax[w] = mx;
  __syncthreads();
  mx = fmaxf(fmaxf(smax[0], smax[1]), fmaxf(smax[2], smax[3]));
  float s = 0.f;
#pragma unroll
  for (int i = 0; i < 4; ++i) {
    v[i].x = __expf(v[i].x - mx);
    v[i].y = __expf(v[i].y - mx);
    v[i].z = __expf(v[i].z - mx);
    v[i].w = __expf(v[i].w - mx);
    s += (v[i].x + v[i].y) + (v[i].z + v[i].w);
  }
#pragma unroll
  for (int o = 32; o; o >>= 1) s += __shfl_xor(s, o, 64);
  if ((t & 63) == 0) ssum[w] = s;
  __syncthreads();
  const float inv = 1.0f / (ssum[0] + ssum[1] + ssum[2] + ssum[3]);
#pragma unroll
  for (int i = 0; i < 4; ++i) {
    v[i].x *= inv; v[i].y *= inv; v[i].z *= inv; v[i].w *= inv;
    r4[t + i * 256] = v[i];
  }
}

extern "C" void kernel_launch(void* const* d_in, const int* in_sizes, int n_in,
                              void* d_out, int out_size, void* d_ws, size_t ws_size,
                              hipStream_t stream) {
  const float* out_state = (const float*)d_in[0];  // [4096,1024]
  const float* history   = (const float*)d_in[1];  // [4096,1024]
  const float* W         = (const float*)d_in[2];  // [1024,1024]
  float* out = (float*)d_out;                      // [4096,4096]

  unsigned short* H2 = (unsigned short*)d_ws;                 // 4096x3072
  unsigned short* W2 = H2 + (size_t)4096 * 3072;              // 1024x3072
  unsigned short* A2 = W2 + (size_t)1024 * 3072;              // 4096x3072
  unsigned short* P2 = A2 + (size_t)4096 * 3072;              // 4096x3072

  split_kernel<<<4096, 256, 0, stream>>>(history, H2, 0);
  split_kernel<<<1024, 256, 0, stream>>>(W, W2, 1);
  split_kernel<<<4096, 256, 0, stream>>>(out_state, A2, 0);

  // proj -> P2 split. 128x128 tile, 8 waves (wave tile 64x32), 2 phases,
  // 4-buf depth-3, vmcnt(4). Grid 32x8 = 256 blocks.
  gemm_bt<128, 128, 2, 4, 2, 1, 32, 8, 4, 3072><<<256, 512, 0, stream>>>(
      H2, W2, nullptr, P2, 4096, 1024);

  // energies -> d_out. 256x256 tile, 8 waves (wave tile 128x64), 2 phases
  // (16 MFMA each, m201 rhythm), 4-buf depth-3, vmcnt(8). 16x16 = 256 blocks.
  gemm_bt<256, 256, 2, 4, 2, 0, 16, 4, 8, 3072><<<256, 512, 0, stream>>>(
      A2, P2, out, nullptr, 4096, 4096);

  softmax_inplace<<<4096, 256, 0, stream>>>(out, 4096);
}